// Round 4
// baseline (243.096 us; speedup 1.0000x reference)
//
#include <hip/hip_runtime.h>

// (B,C,L,H,W) = (4,64,16,32,32), K=1024, D=C=64
constexpr int Cc   = 64;
constexpr int Kc   = 1024;
constexpr int Dc   = 64;
constexpr int LHWc = 16 * 32 * 32;        // 16384
constexpr int Nc   = 4 * LHWc;            // 65536 vectors
constexpr int QSIZE    = 4 * Cc * LHWc;   // 4194304
constexpr int OFF_LOSS = QSIZE;           // 4194304
constexpr int OFF_IDX  = QSIZE + 1;       // 4194305

constexpr int BLK_ROWS = 256;             // rows per block
constexpr int XPAD     = 68;              // LDS row stride (16B aligned)

typedef __attribute__((ext_vector_type(8))) short short8;   // 8 x bf16 bits
typedef __attribute__((ext_vector_type(4))) float f32x4;

static __device__ __forceinline__ unsigned short f2bf(float f) {
    unsigned u = __float_as_uint(f);
    u += 0x7FFFu + ((u >> 16) & 1u);      // RNE (finite data only)
    return (unsigned short)(u >> 16);
}
static __device__ __forceinline__ float bf2f(unsigned short h) {
    return __uint_as_float(((unsigned)h) << 16);
}

// Prep: zero loss; split codebook into bf16 hi/lo (coalesced); exact-chain c2.
__global__ __launch_bounds__(256) void vq_prep(
    const float* __restrict__ cb, float* __restrict__ out,
    unsigned short* __restrict__ cbh, unsigned short* __restrict__ cbl,
    float* __restrict__ c2)
{
    const int t  = threadIdx.x;
    const int k0 = blockIdx.x * 64;
    if (blockIdx.x == 0 && t == 0) out[OFF_LOSS] = 0.0f;

    const int d  = t & 63;
#pragma unroll
    for (int r = 0; r < 16; ++r) {
        const int k = k0 + r * 4 + (t >> 6);
        const float v = cb[(size_t)k * Dc + d];
        unsigned short h = f2bf(v);
        cbh[(size_t)k * Dc + d] = h;
        cbl[(size_t)k * Dc + d] = f2bf(v - bf2f(h));
    }
    if (t < 64) {
        const int k = k0 + t;
        const float* c = cb + (size_t)k * Dc;
        float s = 0.f;
#pragma unroll
        for (int dd = 0; dd < Dc; ++dd) s = __builtin_fmaf(c[dd], c[dd], s);
        c2[k] = s;
    }
}

// 16 waves/block, 256 rows/block, all waves share the same k-order
// (L1 broadcast reuse of codebook), 2-deep register prefetch.
__global__ __launch_bounds__(1024, 4) void vq_main(
    const float* __restrict__ in, const float* __restrict__ codebook,
    const unsigned short* __restrict__ cbh,
    const unsigned short* __restrict__ cbl,
    const float* __restrict__ c2g, float* __restrict__ out)
{
    __shared__ float    xs[BLK_ROWS][XPAD];   // 69632 B
    __shared__ float    xs2[BLK_ROWS];
    __shared__ float    c2s[Kc];
    __shared__ unsigned cand[BLK_ROWS];       // bK | sK<<16
    __shared__ int      kws[BLK_ROWS];

    const int tid  = threadIdx.x;
    const int lane = tid & 63;
    const int w    = __builtin_amdgcn_readfirstlane(tid >> 6);  // 0..15
    const int col  = lane & 15;           // MFMA m/n lane index
    const int g    = lane >> 4;           // MFMA k-slot group
    const int wrow0 = w * 16;             // this wave's 16 rows

    const int bq = blockIdx.x >> 6;                    // batch (64 blk/batch)
    const int p0 = (blockIdx.x & 63) * BLK_ROWS;       // LHW offset
    const size_t inBase = (size_t)bq * (Cc * LHWc) + p0;

    // ---- stage c2 into LDS ----
    c2s[tid] = c2g[tid];

    // ---- stage X[256 rows][64 d] into LDS (coalesced global reads) ----
#pragma unroll
    for (int i = 0; i < 16; ++i) {
        int idx = i * 1024 + tid;
        int d = idx >> 8, row = idx & 255;
        xs[row][d] = in[inBase + (size_t)d * LHWc + row];
    }
    __syncthreads();

    // ---- x2 per row: exact ascending fma chain (recheck only) ----
    if (tid < BLK_ROWS) {
        float s = 0.f;
#pragma unroll
        for (int d = 0; d < Dc; ++d) s = __builtin_fmaf(xs[tid][d], xs[tid][d], s);
        xs2[tid] = s;
    }

    // ---- build A fragments (bf16 hi/lo split), one 16-row tile ----
    short8 xh[2], xl[2];                  // [kt]
#pragma unroll
    for (int kt = 0; kt < 2; ++kt) {
        const float* px = &xs[wrow0 + col][kt * 32 + g * 8];
        f32x4 v0 = *(const f32x4*)px;
        f32x4 v1 = *(const f32x4*)(px + 4);
        short8 h8, l8;
#pragma unroll
        for (int j = 0; j < 4; ++j) {
            unsigned short ha = f2bf(v0[j]);
            h8[j]     = (short)ha;
            l8[j]     = (short)f2bf(v0[j] - bf2f(ha));
            unsigned short hb = f2bf(v1[j]);
            h8[4 + j] = (short)hb;
            l8[4 + j] = (short)f2bf(v1[j] - bf2f(hb));
        }
        xh[kt] = h8; xl[kt] = l8;
    }

    // ---- streaming top-2 state (4 slots = 4 acc regs) ----
    float bV[4], sV[4];
    int   bK[4], sK[4];
#pragma unroll
    for (int r = 0; r < 4; ++r) {
        bV[r] = 3.4e38f; sV[r] = 3.4e38f; bK[r] = 0; sK[r] = 0;
    }

    // ---- 2-deep ping-pong prefetch of B fragments ----
    const unsigned short* hp = cbh + (size_t)col * Dc + g * 8;
    const unsigned short* lp = cbl + (size_t)col * Dc + g * 8;

    short8 Ah0 = *(const short8*)(hp);
    short8 Ah1 = *(const short8*)(hp + 32);
    short8 Al0 = *(const short8*)(lp);
    short8 Al1 = *(const short8*)(lp + 32);
    short8 Bh0 = *(const short8*)(hp + 1024);
    short8 Bh1 = *(const short8*)(hp + 1056);
    short8 Bl0 = *(const short8*)(lp + 1024);
    short8 Bl1 = *(const short8*)(lp + 1056);
    hp += 2048; lp += 2048;               // now points at tile e+2

    const float* c2p = c2s + col;
    int kv = col;

#pragma unroll 1
    for (int cto = 0; cto < 32; ++cto) {
        const float c2a = c2p[0];
        const float c2b = c2p[16];
        c2p += 32;

        // ===== even step: consume A-set =====
        {
            f32x4 acc0 = {0.f, 0.f, 0.f, 0.f};
            f32x4 acc1 = {0.f, 0.f, 0.f, 0.f};
            acc0 = __builtin_amdgcn_mfma_f32_16x16x32_bf16(xh[0], Ah0, acc0, 0, 0, 0);
            acc1 = __builtin_amdgcn_mfma_f32_16x16x32_bf16(xl[0], Ah0, acc1, 0, 0, 0);
            acc0 = __builtin_amdgcn_mfma_f32_16x16x32_bf16(xh[1], Ah1, acc0, 0, 0, 0);
            acc1 = __builtin_amdgcn_mfma_f32_16x16x32_bf16(xl[1], Ah1, acc1, 0, 0, 0);
            f32x4 acc2 = {0.f, 0.f, 0.f, 0.f};
            acc2 = __builtin_amdgcn_mfma_f32_16x16x32_bf16(xh[0], Al0, acc2, 0, 0, 0);
            acc2 = __builtin_amdgcn_mfma_f32_16x16x32_bf16(xh[1], Al1, acc2, 0, 0, 0);
            // reload A-set for tile e+2 (used 1.5 iterations later)
            Ah0 = *(const short8*)(hp);
            Ah1 = *(const short8*)(hp + 32);
            Al0 = *(const short8*)(lp);
            Al1 = *(const short8*)(lp + 32);
#pragma unroll
            for (int r = 0; r < 4; ++r) {
                float a  = acc0[r] + acc1[r] + acc2[r];
                float v  = __builtin_fmaf(-2.f, a, c2a);
                bool  c1 = v < bV[r];
                float nb  = c1 ? v : bV[r];
                int   nbk = c1 ? kv : bK[r];
                float mx  = c1 ? bV[r] : v;
                int   mxk = c1 ? bK[r] : kv;
                bool  c2_ = mx < sV[r];
                sV[r] = c2_ ? mx : sV[r];
                sK[r] = c2_ ? mxk : sK[r];
                bV[r] = nb; bK[r] = nbk;
            }
            kv += 16;
        }

        // ===== odd step: consume B-set =====
        {
            f32x4 acc0 = {0.f, 0.f, 0.f, 0.f};
            f32x4 acc1 = {0.f, 0.f, 0.f, 0.f};
            acc0 = __builtin_amdgcn_mfma_f32_16x16x32_bf16(xh[0], Bh0, acc0, 0, 0, 0);
            acc1 = __builtin_amdgcn_mfma_f32_16x16x32_bf16(xl[0], Bh0, acc1, 0, 0, 0);
            acc0 = __builtin_amdgcn_mfma_f32_16x16x32_bf16(xh[1], Bh1, acc0, 0, 0, 0);
            acc1 = __builtin_amdgcn_mfma_f32_16x16x32_bf16(xl[1], Bh1, acc1, 0, 0, 0);
            f32x4 acc2 = {0.f, 0.f, 0.f, 0.f};
            acc2 = __builtin_amdgcn_mfma_f32_16x16x32_bf16(xh[0], Bl0, acc2, 0, 0, 0);
            acc2 = __builtin_amdgcn_mfma_f32_16x16x32_bf16(xh[1], Bl1, acc2, 0, 0, 0);
            // reload B-set for tile e+3
            Bh0 = *(const short8*)(hp + 1024);
            Bh1 = *(const short8*)(hp + 1056);
            Bl0 = *(const short8*)(lp + 1024);
            Bl1 = *(const short8*)(lp + 1056);
            hp += 2048; lp += 2048;
#pragma unroll
            for (int r = 0; r < 4; ++r) {
                float a  = acc0[r] + acc1[r] + acc2[r];
                float v  = __builtin_fmaf(-2.f, a, c2b);
                bool  c1 = v < bV[r];
                float nb  = c1 ? v : bV[r];
                int   nbk = c1 ? kv : bK[r];
                float mx  = c1 ? bV[r] : v;
                int   mxk = c1 ? bK[r] : kv;
                bool  c2_ = mx < sV[r];
                sV[r] = c2_ ? mx : sV[r];
                sK[r] = c2_ ? mxk : sK[r];
                bV[r] = nb; bK[r] = nbk;
            }
            kv += 16;
        }
    }

    // ---- butterfly top-2 merge across the 16 lanes sharing a row ----
#pragma unroll
    for (int m = 1; m < 16; m <<= 1) {
#pragma unroll
        for (int r = 0; r < 4; ++r) {
            float ob  = __shfl_xor(bV[r], m, 64);
            int   obk = __shfl_xor(bK[r], m, 64);
            float os  = __shfl_xor(sV[r], m, 64);
            int   osk = __shfl_xor(sK[r], m, 64);
            bool  c1 = ob < bV[r];
            float nb  = c1 ? ob : bV[r];
            int   nbk = c1 ? obk : bK[r];
            float mx  = c1 ? bV[r] : ob;
            int   mxk = c1 ? bK[r] : obk;
            bool  c3 = os < sV[r];
            float ms  = c3 ? os : sV[r];
            int   msk = c3 ? osk : sK[r];
            bool  c4 = mx < ms;
            sV[r] = c4 ? mx : ms;
            sK[r] = c4 ? mxk : msk;
            bV[r] = nb; bK[r] = nbk;
        }
    }
    if (col == 0) {
#pragma unroll
        for (int r = 0; r < 4; ++r)
            cand[wrow0 + g * 4 + r] = (unsigned)bK[r] | ((unsigned)sK[r] << 16);
    }
    __syncthreads();

    // ---- exact recheck: 2 candidates/row, 1 thread per (row, candidate) ----
    if (tid < 2 * BLK_ROWS) {
        const int row = tid >> 1;
        const int ci  = tid & 1;
        const unsigned cd = cand[row];
        const int k = ci ? (int)(cd >> 16) : (int)(cd & 0xFFFFu);
        const float* cbr = codebook + (size_t)k * Dc;
        float a = 0.f;
#pragma unroll
        for (int d4 = 0; d4 < 16; ++d4) {
            f32x4 cv = *(const f32x4*)(cbr + d4 * 4);
            const float* xr = &xs[row][d4 * 4];
            a = __builtin_fmaf(xr[0], cv[0], a);
            a = __builtin_fmaf(xr[1], cv[1], a);
            a = __builtin_fmaf(xr[2], cv[2], a);
            a = __builtin_fmaf(xr[3], cv[3], a);
        }
        float d2 = __builtin_fmaf(-2.f, a, xs2[row]) + c2g[k];
        unsigned long long pk =
            ((unsigned long long)__float_as_uint(d2) << 32) | (unsigned)k;
        unsigned long long o = __shfl_xor(pk, 1, 64);
        pk = o < pk ? o : pk;                // min d2, ties -> lowest k
        if (ci == 0) {
            const int kwin = (int)(pk & 0xFFFFFFFFu);
            kws[row] = kwin;
            out[OFF_IDX + (size_t)blockIdx.x * BLK_ROWS + row] = (float)kwin;
        }
    }
    __syncthreads();

    // ---- quantized write + loss: 4 threads per row, 16 channels each ----
    {
        const int row = tid & 255;
        const int cp  = tid >> 8;            // 0..3
        const int kw  = kws[row];
        const float* cbw = codebook + (size_t)kw * Dc + cp * 16;
        float* qout = out + inBase + row;
        float ls = 0.f;
#pragma unroll
        for (int j = 0; j < 16; ++j) {
            const int c = cp * 16 + j;
            float qv = cbw[j];
            qout[(size_t)c * LHWc] = qv;     // coalesced across lanes per c
            float e = qv - xs[row][c];
            ls = __builtin_fmaf(e, e, ls);
        }
#pragma unroll
        for (int off = 32; off > 0; off >>= 1) ls += __shfl_down(ls, off, 64);
        if (lane == 0) atomicAdd(&out[OFF_LOSS], ls * (1.25f / (float)QSIZE));
    }
}

extern "C" void kernel_launch(void* const* d_in, const int* in_sizes, int n_in,
                              void* d_out, int out_size, void* d_ws, size_t ws_size,
                              hipStream_t stream) {
    const float* in = (const float*)d_in[0];   // [4,64,16,32,32] f32
    const float* cb = (const float*)d_in[1];   // [1024,64] f32
    float* out = (float*)d_out;
    (void)in_sizes; (void)n_in; (void)out_size; (void)ws_size;

    unsigned short* cbh = (unsigned short*)d_ws;                 // 128 KB
    unsigned short* cbl = cbh + (size_t)Kc * Dc;                 // 128 KB
    float*          c2  = (float*)(cbl + (size_t)Kc * Dc);       // 4 KB

    vq_prep<<<dim3(16), dim3(256), 0, stream>>>(cb, out, cbh, cbl, c2);
    vq_main<<<dim3(Nc / BLK_ROWS), dim3(1024), 0, stream>>>(in, cb, cbh, cbl, c2, out);
}

// Round 5
// 139.303 us; speedup vs baseline: 1.7451x; 1.7451x over previous
//
#include <hip/hip_runtime.h>

// (B,C,L,H,W) = (4,64,16,32,32), K=1024, D=C=64
constexpr int Cc   = 64;
constexpr int Kc   = 1024;
constexpr int Dc   = 64;
constexpr int LHWc = 16 * 32 * 32;        // 16384
constexpr int Nc   = 4 * LHWc;            // 65536 vectors
constexpr int QSIZE    = 4 * Cc * LHWc;   // 4194304
constexpr int OFF_LOSS = QSIZE;           // 4194304
constexpr int OFF_IDX  = QSIZE + 1;       // 4194305

constexpr int BLK_ROWS = 256;             // rows per block
constexpr int XPAD     = 68;              // LDS row stride (16B aligned)

typedef __attribute__((ext_vector_type(8))) short short8;   // 8 x bf16 bits
typedef __attribute__((ext_vector_type(4))) float f32x4;

static __device__ __forceinline__ unsigned short f2bf(float f) {
    unsigned u = __float_as_uint(f);
    u += 0x7FFFu + ((u >> 16) & 1u);      // RNE (finite data only)
    return (unsigned short)(u >> 16);
}
static __device__ __forceinline__ float bf2f(unsigned short h) {
    return __uint_as_float(((unsigned)h) << 16);
}

// Prep: zero loss; split codebook into bf16 hi/lo (coalesced); exact-chain c2.
__global__ __launch_bounds__(256) void vq_prep(
    const float* __restrict__ cb, float* __restrict__ out,
    unsigned short* __restrict__ cbh, unsigned short* __restrict__ cbl,
    float* __restrict__ c2)
{
    const int t  = threadIdx.x;
    const int k0 = blockIdx.x * 64;
    if (blockIdx.x == 0 && t == 0) out[OFF_LOSS] = 0.0f;

    const int d  = t & 63;
#pragma unroll
    for (int r = 0; r < 16; ++r) {
        const int k = k0 + r * 4 + (t >> 6);
        const float v = cb[(size_t)k * Dc + d];
        unsigned short h = f2bf(v);
        cbh[(size_t)k * Dc + d] = h;
        cbl[(size_t)k * Dc + d] = f2bf(v - bf2f(h));
    }
    if (t < 64) {
        const int k = k0 + t;
        const float* c = cb + (size_t)k * Dc;
        float s = 0.f;
#pragma unroll
        for (int dd = 0; dd < Dc; ++dd) s = __builtin_fmaf(c[dd], c[dd], s);
        c2[k] = s;
    }
}

// Codebook-stationary: 8 waves x 128 codes in registers (A-operand),
// X streamed from LDS in pre-built bf16 hi/lo fragment layout (B-operand).
__global__ __launch_bounds__(512, 2) void vq_main(
    const float* __restrict__ in, const float* __restrict__ codebook,
    const unsigned short* __restrict__ cbh,
    const unsigned short* __restrict__ cbl,
    const float* __restrict__ c2g, float* __restrict__ out)
{
    __shared__ float  xs[BLK_ROWS][XPAD];     // 69632 B
    __shared__ float  xs2[BLK_ROWS];          // 1024
    __shared__ short8 xfh[2048];              // 32768: [t][kt][lane] 16B chunks
    __shared__ short8 xfl[2048];              // 32768
    __shared__ float  candV1[8][BLK_ROWS];    // 8192: per-wave best value
    __shared__ float  candV2[8][BLK_ROWS];    // 8192: per-wave 2nd value
    __shared__ unsigned candKs[8][BLK_ROWS];  // 8192: bK | sK<<16
    __shared__ int    kws[BLK_ROWS];          // 1024     (total 161792 B)

    const int tid  = threadIdx.x;
    const int lane = tid & 63;
    const int w    = __builtin_amdgcn_readfirstlane(tid >> 6);  // 0..7
    const int col  = lane & 15;           // output n = X row within tile
    const int g    = lane >> 4;           // k-chunk / output m-group

    const int bq = blockIdx.x >> 6;                    // batch (64 blk/batch)
    const int p0 = (blockIdx.x & 63) * BLK_ROWS;       // LHW offset
    const size_t inBase = (size_t)bq * (Cc * LHWc) + p0;

    // ---- stage X[256 rows][64 d] into LDS (coalesced) ----
#pragma unroll
    for (int i = 0; i < 32; ++i) {
        int idx = i * 512 + tid;
        int d = idx >> 8, row = idx & 255;
        xs[row][d] = in[inBase + (size_t)d * LHWc + row];
    }
    __syncthreads();

    // ---- x2 per row: exact ascending fma chain (ref-identical) ----
    if (tid < BLK_ROWS) {
        float s = 0.f;
#pragma unroll
        for (int d = 0; d < Dc; ++d) s = __builtin_fmaf(xs[tid][d], xs[tid][d], s);
        xs2[tid] = s;
    }

    // ---- build X fragments (bf16 hi/lo) into LDS, chunk c = t*128+kt*64+lane ----
#pragma unroll
    for (int j = 0; j < 4; ++j) {
        const int c  = tid + j * 512;
        const int t  = c >> 7;
        const int kt = (c >> 6) & 1;
        const int l  = c & 63;
        const int row = t * 16 + (l & 15);
        const int d0  = kt * 32 + (l >> 4) * 8;
        f32x4 v0 = *(const f32x4*)&xs[row][d0];
        f32x4 v1 = *(const f32x4*)&xs[row][d0 + 4];
        short8 h8, l8;
#pragma unroll
        for (int e = 0; e < 4; ++e) {
            unsigned short ha = f2bf(v0[e]);
            h8[e]     = (short)ha;
            l8[e]     = (short)f2bf(v0[e] - bf2f(ha));
            unsigned short hb = f2bf(v1[e]);
            h8[4 + e] = (short)hb;
            l8[4 + e] = (short)f2bf(v1[e] - bf2f(hb));
        }
        xfh[c] = h8; xfl[c] = l8;
    }
    __syncthreads();

    // ---- load this wave's 128 codes as A-fragments (ONCE) + c2 regs ----
    short8 Ah[8][2], Al[8][2];
    const size_t cbase = (size_t)(w * 128 + col) * Dc + g * 8;
#pragma unroll
    for (int ct = 0; ct < 8; ++ct) {
#pragma unroll
        for (int kt = 0; kt < 2; ++kt) {
            Ah[ct][kt] = *(const short8*)(cbh + cbase + ct * 16 * Dc + kt * 32);
            Al[ct][kt] = *(const short8*)(cbl + cbase + ct * 16 * Dc + kt * 32);
        }
    }
    float c2r[8][4];
#pragma unroll
    for (int ct = 0; ct < 8; ++ct)
#pragma unroll
        for (int r = 0; r < 4; ++r)
            c2r[ct][r] = c2g[w * 128 + ct * 16 + g * 4 + r];
    const int kbl = w * 128 + g * 4;      // + ct*16 + r at use

    // ---- main loop: 16 X-tiles, codes stay in registers ----
#pragma unroll 1
    for (int t = 0; t < 16; ++t) {
        const short8 xh0 = xfh[t * 128 + lane];
        const short8 xh1 = xfh[t * 128 + 64 + lane];
        const short8 xl0 = xfl[t * 128 + lane];
        const short8 xl1 = xfl[t * 128 + 64 + lane];
        const float  x2l = xs2[t * 16 + col];

        float bV = 3.4e38f, sV = 3.4e38f;
        int   bK = 0, sK = 0;

#pragma unroll
        for (int ct = 0; ct < 8; ++ct) {
            f32x4 acc = {0.f, 0.f, 0.f, 0.f};
            // split-3 dot: ch*xh + ch*xl + cl*xh  (ll dropped, ~1e-8)
            acc = __builtin_amdgcn_mfma_f32_16x16x32_bf16(Ah[ct][0], xh0, acc, 0, 0, 0);
            acc = __builtin_amdgcn_mfma_f32_16x16x32_bf16(Ah[ct][1], xh1, acc, 0, 0, 0);
            acc = __builtin_amdgcn_mfma_f32_16x16x32_bf16(Ah[ct][0], xl0, acc, 0, 0, 0);
            acc = __builtin_amdgcn_mfma_f32_16x16x32_bf16(Ah[ct][1], xl1, acc, 0, 0, 0);
            acc = __builtin_amdgcn_mfma_f32_16x16x32_bf16(Al[ct][0], xh0, acc, 0, 0, 0);
            acc = __builtin_amdgcn_mfma_f32_16x16x32_bf16(Al[ct][1], xh1, acc, 0, 0, 0);
#pragma unroll
            for (int r = 0; r < 4; ++r) {
                // reference rounding structure: fl(fl(x2 - 2a) + c2)
                float d2 = __builtin_fmaf(-2.f, acc[r], x2l);
                float v  = d2 + c2r[ct][r];
                int   k  = kbl + ct * 16 + r;
                bool  c1 = v < bV;
                float nb  = c1 ? v : bV;
                int   nbk = c1 ? k : bK;
                float mx  = c1 ? bV : v;
                int   mxk = c1 ? bK : k;
                bool  c2_ = mx < sV;
                sV = c2_ ? mx : sV;
                sK = c2_ ? mxk : sK;
                bV = nb; bK = nbk;
            }
        }

        // butterfly over g (lanes ^16, ^32): top-2 of wave's 128 codes per row
#pragma unroll
        for (int m = 16; m <= 32; m <<= 1) {
            float ob  = __shfl_xor(bV, m, 64);
            int   obk = __shfl_xor(bK, m, 64);
            float os  = __shfl_xor(sV, m, 64);
            int   osk = __shfl_xor(sK, m, 64);
            bool  c1 = ob < bV;
            float nb  = c1 ? ob : bV;
            int   nbk = c1 ? obk : bK;
            float mx  = c1 ? bV : ob;
            int   mxk = c1 ? bK : obk;
            bool  c3 = os < sV;
            float ms  = c3 ? os : sV;
            int   msk = c3 ? osk : sK;
            bool  c4 = mx < ms;
            sV = c4 ? mx : ms;
            sK = c4 ? mxk : msk;
            bV = nb; bK = nbk;
        }
        if (g == 0) {
            const int row = t * 16 + col;
            candV1[w][row] = bV;
            candV2[w][row] = sV;
            candKs[w][row] = (unsigned)bK | ((unsigned)sK << 16);
        }
    }
    __syncthreads();

    // ---- cross-wave merge: global top-2 per row (value, ties -> low k) ----
    if (tid < BLK_ROWS) {
        const int row = tid;
        unsigned long long b = ~0ull, s = ~0ull;
#pragma unroll
        for (int wv = 0; wv < 8; ++wv) {
            unsigned ks = candKs[wv][row];
            unsigned long long p1 =
                ((unsigned long long)__float_as_uint(candV1[wv][row]) << 32) | (ks & 0xFFFFu);
            unsigned long long p2 =
                ((unsigned long long)__float_as_uint(candV2[wv][row]) << 32) | (ks >> 16);
            unsigned long long nb = p1 < b ? p1 : b;
            unsigned long long mx = p1 < b ? b : p1;
            s = mx < s ? mx : s; b = nb;
            nb = p2 < b ? p2 : b;
            mx = p2 < b ? b : p2;
            s = mx < s ? mx : s; b = nb;
        }
        kws[row] = (int)((b & 0x3FFu) | ((s & 0x3FFu) << 16));
    }
    __syncthreads();

    // ---- exact recheck: 2 candidates/row, ref-structured f32 chain ----
    {
        const int row = tid >> 1;
        const int ci  = tid & 1;
        const int pr  = kws[row];
        const int k   = ci ? ((pr >> 16) & 0x3FF) : (pr & 0x3FF);
        const float* cbr = codebook + (size_t)k * Dc;
        float a0 = 0.f, a1 = 0.f, a2 = 0.f, a3 = 0.f;
#pragma unroll
        for (int d16 = 0; d16 < 4; ++d16) {
            f32x4 cv0 = *(const f32x4*)(cbr + d16 * 16);
            f32x4 cv1 = *(const f32x4*)(cbr + d16 * 16 + 4);
            f32x4 cv2 = *(const f32x4*)(cbr + d16 * 16 + 8);
            f32x4 cv3 = *(const f32x4*)(cbr + d16 * 16 + 12);
            const float* xr = &xs[row][d16 * 16];
#pragma unroll
            for (int e = 0; e < 4; ++e) {
                a0 = __builtin_fmaf(xr[e],      cv0[e], a0);
                a1 = __builtin_fmaf(xr[4 + e],  cv1[e], a1);
                a2 = __builtin_fmaf(xr[8 + e],  cv2[e], a2);
                a3 = __builtin_fmaf(xr[12 + e], cv3[e], a3);
            }
        }
        float a  = (a0 + a1) + (a2 + a3);
        float d2 = __builtin_fmaf(-2.f, a, xs2[row]) + c2g[k];
        unsigned long long pk =
            ((unsigned long long)__float_as_uint(d2) << 32) | (unsigned)k;
        unsigned long long o = __shfl_xor(pk, 1, 64);
        pk = o < pk ? o : pk;            // min d2, ties -> lowest k
        if (ci == 0) {
            const int kwin = (int)(pk & 0x3FFu);
            kws[row] = kwin;
            out[OFF_IDX + (size_t)blockIdx.x * BLK_ROWS + row] = (float)kwin;
        }
    }
    __syncthreads();

    // ---- quantized write + loss: 2 threads per row, 32 channels each ----
    {
        const int row = tid & 255;
        const int cp  = tid >> 8;            // 0..1
        const int kw  = kws[row];
        const float* cbw = codebook + (size_t)kw * Dc + cp * 32;
        float* qout = out + inBase + row;
        float ls = 0.f;
#pragma unroll
        for (int j = 0; j < 32; ++j) {
            const int c = cp * 32 + j;
            float qv = cbw[j];
            qout[(size_t)c * LHWc] = qv;     // coalesced across lanes per c
            float e = qv - xs[row][c];
            ls = __builtin_fmaf(e, e, ls);
        }
#pragma unroll
        for (int off = 32; off > 0; off >>= 1) ls += __shfl_down(ls, off, 64);
        if (lane == 0) atomicAdd(&out[OFF_LOSS], ls * (1.25f / (float)QSIZE));
    }
}

extern "C" void kernel_launch(void* const* d_in, const int* in_sizes, int n_in,
                              void* d_out, int out_size, void* d_ws, size_t ws_size,
                              hipStream_t stream) {
    const float* in = (const float*)d_in[0];   // [4,64,16,32,32] f32
    const float* cb = (const float*)d_in[1];   // [1024,64] f32
    float* out = (float*)d_out;
    (void)in_sizes; (void)n_in; (void)out_size; (void)ws_size;

    unsigned short* cbh = (unsigned short*)d_ws;                 // 128 KB
    unsigned short* cbl = cbh + (size_t)Kc * Dc;                 // 128 KB
    float*          c2  = (float*)(cbl + (size_t)Kc * Dc);       // 4 KB

    vq_prep<<<dim3(16), dim3(256), 0, stream>>>(cb, out, cbh, cbl, c2);
    vq_main<<<dim3(Nc / BLK_ROWS), dim3(512), 0, stream>>>(in, cb, cbh, cbl, c2, out);
}